// Round 6
// baseline (1583.223 us; speedup 1.0000x reference)
//
#include <hip/hip_runtime.h>

#define B_ 8
#define N_ 2048
#define D_ 1024
#define M_ (B_*N_)          // 16384 rows
#define SEGS 64
#define EPB (4096/SEGS)     // 64 events per segment
#define CW 256              // scan chunk width (cols per block)

typedef __attribute__((ext_vector_type(8))) short short8;
typedef __attribute__((ext_vector_type(4))) float floatx4;

__device__ __forceinline__ ushort f2bf(float f) {
  unsigned u = __builtin_bit_cast(unsigned, f);
  return (ushort)((u + 0x7fffu + ((u >> 16) & 1u)) >> 16);
}
__device__ __forceinline__ float bf2f(ushort u) {
  return __builtin_bit_cast(float, ((unsigned)u) << 16);
}
__device__ __forceinline__ void gload16(const void* g, void* l) {
  __builtin_amdgcn_global_load_lds(
      (const __attribute__((address_space(1))) unsigned*)g,
      (__attribute__((address_space(3))) unsigned*)l, 16, 0, 0);
}
__device__ __forceinline__ float sig4(float h) {
  // sigmoid(4*(h-1))
  return 1.0f / (1.0f + __expf(4.0f - 4.0f*h));
}

// ---------------- conversions ----------------
__global__ __launch_bounds__(256) void conv_x_k(const float4* __restrict__ x,
                                                ushort4* __restrict__ o) {
  int i = blockIdx.x * 256 + threadIdx.x;
  float4 f = x[i];
  ushort4 u;
  u.x = f2bf(f.x); u.y = f2bf(f.y); u.z = f2bf(f.z); u.w = f2bf(f.w);
  o[i] = u;
}

// all 4 weight transposes in one launch; z selects the matrix
__global__ __launch_bounds__(256) void transpose_k(
    const float* __restrict__ Wq, const float* __restrict__ Wk,
    const float* __restrict__ Wv, const float* __restrict__ Wo,
    ushort* __restrict__ W3T, ushort* __restrict__ WoT) {
  __shared__ float tile[32][33];
  int z = blockIdx.z;
  const float* W = (z == 0) ? Wq : (z == 1) ? Wk : (z == 2) ? Wv : Wo;
  ushort* WT = (z < 3) ? (W3T + (size_t)z * D_ * D_) : WoT;
  int tx = threadIdx.x, ty = threadIdx.y;
  int x = blockIdx.x * 32 + tx;
  int y = blockIdx.y * 32 + ty;
#pragma unroll
  for (int j = 0; j < 32; j += 8)
    tile[ty + j][tx] = W[(size_t)(y + j) * D_ + x];
  __syncthreads();
  int x2 = blockIdx.y * 32 + tx;
  int y2 = blockIdx.x * 32 + ty;
#pragma unroll
  for (int j = 0; j < 32; j += 8)
    WT[(size_t)(y2 + j) * D_ + x2] = f2bf(tile[tx][ty + j]);
}

// ---------------- 256x256 8-wave GEMM mainloop, 2-slot ring, 2 blocks/CU ----
// ROUND-6 STRUCTURE CHANGE: rounds 2-5 ran 1 block/CU (128 KB LDS) -> 2
// waves/SIMD in ONE barrier group -> every vmcnt/lgkm wait stalled the whole
// SIMD (lockstep, MfmaUtil pinned ~31%). Fix per m97/m114: 2-slot ring
// (64 KB LDS) -> 2 independent blocks/CU -> block A's barrier drain overlaps
// block B's MFMA. One __syncthreads per K-tile (compiler emits the exact
// vmcnt(0)+lgkmcnt(0) drain); stage(k+1) issued right after the sync into the
// slot whose readers (tile k-1) are provably done (each wave's own ds_reads
// retire before its barrier arrival). No hand-rolled waitcnt asm.
//
// LDS layout per slot: 256 rows x 32 bf16; physical 16B-chunk c of row r
// holds logical chunk (c-(r>>1))&3 -> 2 lanes/16B-slot on ds_read_b128
// (2-way aliasing is free, m136; measured SQ_LDS_BANK_CONFLICT=0).
// global_load_lds writes linearly; inverse swizzle on the global source.
__device__ __forceinline__ void mainloop256(
    const ushort* __restrict__ Ab, const ushort* __restrict__ Bb,
    ushort* __restrict__ As, ushort* __restrict__ Bs, int t,
    floatx4 (&acc)[8][4])
{
  const int lane = t & 63, wid = t >> 6;
  const int quad = lane >> 4, l15 = lane & 15;
  const int wm = wid >> 2, wn = wid & 3;

  // staging addresses: li = r*512+t enumerates 1024 16B chunks of a slot
  int srcO[2], dsto[2];
#pragma unroll
  for (int r = 0; r < 2; r++) {
    int li = r * 512 + t;
    int row = li >> 2, c = li & 3;
    int soff = ((c - (row >> 1)) & 3) * 8;       // inverse swizzle on source
    srcO[r] = row * D_ + soff;
    dsto[r] = li * 16;
  }

  // fragment read offsets (ushort units), loop-invariant
  int offA[8], offB[4];
#pragma unroll
  for (int i = 0; i < 8; i++) {
    int row = wm * 128 + i * 16 + l15;
    offA[i] = row * 32 + ((quad + (row >> 1)) & 3) * 8;
  }
#pragma unroll
  for (int i = 0; i < 4; i++) {
    int row = wn * 64 + i * 16 + l15;
    offB[i] = row * 32 + ((quad + (row >> 1)) & 3) * 8;
  }

  // prologue: stage tile 0 into slot 0
#pragma unroll
  for (int r = 0; r < 2; r++) {
    gload16(Ab + srcO[r], (char*)As + dsto[r]);
    gload16(Bb + srcO[r], (char*)Bs + dsto[r]);
  }

  const int NT = D_ / 32;  // 32 K-tiles
#pragma unroll 2
  for (int tt = 0; tt < NT; tt++) {
    __syncthreads();   // drains vmcnt(0)+lgkmcnt(0): slot tt&1 ready,
                       // slot (tt+1)&1's readers (tile tt-1) all done
    const ushort* Asl = As + (tt & 1) * 8192;
    const ushort* Bsl = Bs + (tt & 1) * 8192;
    if (tt + 1 < NT) {
      ushort* dA = As + ((tt + 1) & 1) * 8192;
      ushort* dB = Bs + ((tt + 1) & 1) * 8192;
#pragma unroll
      for (int r = 0; r < 2; r++) {
        gload16(Ab + srcO[r] + (tt + 1) * 32, (char*)dA + dsto[r]);
        gload16(Bb + srcO[r] + (tt + 1) * 32, (char*)dB + dsto[r]);
      }
    }
    short8 af[4], bfr[4], ag[4];
#pragma unroll
    for (int i = 0; i < 4; i++) af[i] = *(const short8*)(Asl + offA[i]);
#pragma unroll
    for (int i = 0; i < 4; i++) bfr[i] = *(const short8*)(Bsl + offB[i]);
    __builtin_amdgcn_s_setprio(1);
#pragma unroll
    for (int tm = 0; tm < 4; tm++)
#pragma unroll
      for (int tn = 0; tn < 4; tn++)
        acc[tm][tn] = __builtin_amdgcn_mfma_f32_16x16x32_bf16(
            af[tm], bfr[tn], acc[tm][tn], 0, 0, 0);
    __builtin_amdgcn_s_setprio(0);
#pragma unroll
    for (int i = 0; i < 4; i++) ag[i] = *(const short8*)(Asl + offA[4 + i]);
    __builtin_amdgcn_s_setprio(1);
#pragma unroll
    for (int tm = 0; tm < 4; tm++)
#pragma unroll
      for (int tn = 0; tn < 4; tn++)
        acc[4 + tm][tn] = __builtin_amdgcn_mfma_f32_16x16x32_bf16(
            ag[tm], bfr[tn], acc[4 + tm][tn], 0, 0, 0);
    __builtin_amdgcn_s_setprio(0);
  }
}

// ---------------- fused QKV GEMM, 256^2 tile, XCD-aware ----------------
// 768 blocks: xcd = lin&7; 96 slots/XCD = 3 z x 8 m-groups x 4 n-tiles.
__global__ __launch_bounds__(512, 4) void gemm_qkv_k(
    const ushort* __restrict__ A, const ushort* __restrict__ W3T,
    const float* __restrict__ gq, const float* __restrict__ bq,
    const float* __restrict__ mq, const float* __restrict__ vq,
    const float* __restrict__ gk, const float* __restrict__ bk,
    const float* __restrict__ mk, const float* __restrict__ vk,
    const float* __restrict__ gv, const float* __restrict__ bv,
    const float* __restrict__ mv, const float* __restrict__ vv,
    float* __restrict__ rsQ, float* __restrict__ rsK, ushort* __restrict__ Vb)
{
  __shared__ ushort As[2 * 8192];   // 32 KB
  __shared__ ushort Bs[2 * 8192];   // 32 KB  -> 64 KB total: 2 blocks/CU
  const int t = threadIdx.x;
  const int lane = t & 63, wid = t >> 6;
  const int quad = lane >> 4, l15 = lane & 15;
  const int wm = wid >> 2, wn = wid & 3;

  const int lin = blockIdx.x;
  const int xcd = lin & 7, s = lin >> 3;   // 96 slots per XCD
  const int z = s >> 5;                    // 0..2
  const int rem = s & 31;
  const int mg = rem >> 2;                 // 0..7
  const int nt = rem & 3;                  // 0..3
  const int tileM = (xcd * 8 + mg) * 256;
  const int tileN = nt * 256;

  floatx4 acc[8][4];
#pragma unroll
  for (int i = 0; i < 8; i++)
#pragma unroll
    for (int j = 0; j < 4; j++) acc[i][j] = (floatx4){0.f, 0.f, 0.f, 0.f};

  mainloop256(A + (size_t)tileM * D_,
              W3T + (size_t)z * D_ * D_ + (size_t)tileN * D_,
              As, Bs, t, acc);

  // BN params in the epilogue (keeps mainloop VGPR pressure minimal)
  const float* gg  = (z == 0) ? gq : (z == 1) ? gk : gv;
  const float* bb  = (z == 0) ? bq : (z == 1) ? bk : bv;
  const float* mmn = (z == 0) ? mq : (z == 1) ? mk : mv;
  const float* vvn = (z == 0) ? vq : (z == 1) ? vk : vv;
  float sc[4], sh[4];
#pragma unroll
  for (int tn = 0; tn < 4; tn++) {
    int col = tileN + wn * 64 + tn * 16 + l15;
    float scv = gg[col] * rsqrtf(vvn[col] + 1e-5f);
    sc[tn] = scv;
    sh[tn] = bb[col] - mmn[col] * scv;
  }

  if (z == 2) {
#pragma unroll
    for (int tm = 0; tm < 8; tm++) {
      int row0 = tileM + wm * 128 + tm * 16 + quad * 4;
#pragma unroll
      for (int tn = 0; tn < 4; tn++) {
        int col = tileN + wn * 64 + tn * 16 + l15;
#pragma unroll
        for (int r = 0; r < 4; r++)
          Vb[(size_t)(row0 + r) * D_ + col] =
              f2bf(sig4(acc[tm][tn][r] * sc[tn] + sh[tn]));
      }
    }
  } else {
    float* rowsum = (z == 0) ? rsQ : rsK;
#pragma unroll
    for (int tm = 0; tm < 8; tm++) {
      float rs[4] = {0.f, 0.f, 0.f, 0.f};
#pragma unroll
      for (int tn = 0; tn < 4; tn++)
#pragma unroll
        for (int r = 0; r < 4; r++)
          rs[r] += sig4(acc[tm][tn][r] * sc[tn] + sh[tn]);
#pragma unroll
      for (int off = 1; off < 16; off <<= 1)
#pragma unroll
        for (int r = 0; r < 4; r++)
          rs[r] += __shfl_xor(rs[r], off, 64);
      if (l15 == 0) {
        int row0 = tileM + wm * 128 + tm * 16 + quad * 4;
#pragma unroll
        for (int r = 0; r < 4; r++)
          atomicAdd(&rowsum[row0 + r], rs[r]);
      }
    }
  }
}

// ---------------- final GEMM: AVb @ WoT^T + bo -> fp32, 256^2 tile ----------
__global__ __launch_bounds__(512, 4) void gemm_out_k(
    const ushort* __restrict__ A, const ushort* __restrict__ Bt,
    float* __restrict__ outF, const float* __restrict__ bo)
{
  __shared__ ushort As[2 * 8192];
  __shared__ ushort Bs[2 * 8192];
  const int t = threadIdx.x;
  const int lane = t & 63, wid = t >> 6;
  const int quad = lane >> 4, l15 = lane & 15;
  const int wm = wid >> 2, wn = wid & 3;

  const int lin = blockIdx.x;
  const int xcd = lin & 7, s = lin >> 3;   // 32 slots per XCD
  const int mg = s >> 2, nt = s & 3;
  const int tileM = (xcd * 8 + mg) * 256;
  const int tileN = nt * 256;

  floatx4 acc[8][4];
#pragma unroll
  for (int i = 0; i < 8; i++)
#pragma unroll
    for (int j = 0; j < 4; j++) acc[i][j] = (floatx4){0.f, 0.f, 0.f, 0.f};

  mainloop256(A + (size_t)tileM * D_, Bt + (size_t)tileN * D_, As, Bs, t, acc);

#pragma unroll
  for (int tn = 0; tn < 4; tn++) {
    int col = tileN + wn * 64 + tn * 16 + l15;
    float bias = bo[col];
#pragma unroll
    for (int tm = 0; tm < 8; tm++) {
      int row0 = tileM + wm * 128 + tm * 16 + quad * 4;
#pragma unroll
      for (int r = 0; r < 4; r++)
        outF[(size_t)(row0 + r) * D_ + col] = acc[tm][tn][r] + bias;
    }
  }
}

// ---------------- rank-by-counting event sort ----------------
__global__ __launch_bounds__(256) void rank_events_k(
    const float* __restrict__ rsQ, const float* __restrict__ rsK,
    int* __restrict__ evt_tag, float* __restrict__ evt_wa, float* __restrict__ evt_wd)
{
  __shared__ unsigned long long keys[4096];  // 32 KB
  __shared__ int part[256];
  int b = blockIdx.y, chunk = blockIdx.x;
  int t = threadIdx.x;
  for (int i = t; i < 4096; i += 256) {
    float v; unsigned tag;
    if (i < 2048) {
      v = 1.0f - rsQ[b * N_ + i] * (1.0f / 1024.0f);
      tag = (unsigned)i | 0x10000u;          // query
    } else {
      int j = i - 2048;
      v = 1.0f - rsK[b * N_ + j] * (1.0f / 1024.0f);
      tag = (unsigned)j;                     // key
    }
    keys[i] = ((unsigned long long)__builtin_bit_cast(unsigned, v) << 32) | tag;
  }
  __syncthreads();
  int e = chunk * 128 + (t & 127);
  int j0 = (t >> 7) * 2048;
  unsigned long long me = keys[e];
  int r = 0;
#pragma unroll 8
  for (int j = 0; j < 2048; j++) r += (keys[j0 + j] < me) ? 1 : 0;
  part[t] = r;
  __syncthreads();
  if (t < 128) {
    int rank = part[t] + part[t + 128];
    unsigned tag = (unsigned)(me & 0x1FFFFu);
    float v = __builtin_bit_cast(float, (unsigned)(me >> 32));
    bool isq = (tag & 0x10000u) != 0;
    int o = b * 4096 + rank;
    evt_tag[o] = (int)tag;
    // keys: wa=e^{2tk}, wd=e^{-2tk};  queries: wa=e^{-2tq}, wd=e^{2tq}
    evt_wa[o] = isq ? expf(-2.0f * v) : expf(2.0f * v);
    evt_wd[o] = isq ? expf(2.0f * v) : expf(-2.0f * v);
  }
}

// ---------------- segment totals (branch-free, pipelined) ----------------
__global__ __launch_bounds__(256) void seg_tot_k(
    const int* __restrict__ evt_tag, const float* __restrict__ evt_wa,
    const float* __restrict__ evt_wd, const ushort* __restrict__ Vb,
    float* __restrict__ totWA, float* __restrict__ totWD, float* __restrict__ totP)
{
  __shared__ int srow[EPB];
  __shared__ float swa[EPB], swd[EPB], spw[EPB];
  int b = blockIdx.z, seg = blockIdx.y, chunk = blockIdx.x;
  int t = threadIdx.x;
  int e0 = b * 4096 + seg * EPB;
  if (t < EPB) {
    int tg = evt_tag[e0 + t];
    bool isk = !(tg & 0x10000);
    srow[t] = isk ? (tg & 0xFFFF) : 0;
    swa[t] = isk ? evt_wa[e0 + t] : 0.f;
    swd[t] = isk ? evt_wd[e0 + t] : 0.f;
    spw[t] = isk ? 1.f : 0.f;
  }
  __syncthreads();
  int c = chunk * 512 + t * 2;
  const ushort* vb = Vb + (size_t)b * N_ * D_ + c;
  float wa0 = 0, wa1 = 0, wd0 = 0, wd1 = 0, p0 = 0, p1 = 0;
#pragma unroll 8
  for (int e = 0; e < EPB; e++) {
    unsigned raw = *(const unsigned*)(vb + (size_t)srow[e] * D_);
    float v0 = bf2f((ushort)(raw & 0xffffu)), v1 = bf2f((ushort)(raw >> 16));
    float wa = swa[e], wd = swd[e], pw = spw[e];
    wa0 += wa * v0; wa1 += wa * v1;
    wd0 += wd * v0; wd1 += wd * v1;
    p0 += pw * v0;  p1 += pw * v1;
  }
  size_t o = ((size_t)b * SEGS + seg) * D_ + c;
  totWA[o] = wa0; totWA[o + 1] = wa1;
  totWD[o] = wd0; totWD[o + 1] = wd1;
  totP[o]  = p0;  totP[o + 1]  = p1;
}

// ---------------- cross-segment prefix/suffix: register-resident scan -------
// Three sequential passes, ONE 64-float register array reused (caps peak
// register-array pressure at 64; full unroll -> static indexing, no scratch).
__global__ __launch_bounds__(256) void seg_prefix_k(
    const float* __restrict__ totWA, const float* __restrict__ totWD,
    const float* __restrict__ totP,
    float* __restrict__ preA, float* __restrict__ sufD,
    float* __restrict__ Vsum)
{
  int b = blockIdx.y;
  int c = blockIdx.x * 256 + threadIdx.x;
  size_t base = (size_t)b * SEGS * D_ + c;

  float va[SEGS];
#pragma unroll
  for (int s = 0; s < SEGS; s++)
    va[s] = totWA[base + (size_t)s * D_];
  float a = 0.f;
#pragma unroll
  for (int s = 0; s < SEGS; s++) {
    preA[base + (size_t)s * D_] = a;
    a += va[s];
  }

#pragma unroll
  for (int s = 0; s < SEGS; s++)
    va[s] = totWD[base + (size_t)s * D_];
  float d = 0.f;
#pragma unroll
  for (int s = SEGS - 1; s >= 0; s--) {
    sufD[base + (size_t)s * D_] = d;
    d += va[s];
  }

  float psum = 0.f;
#pragma unroll
  for (int s = 0; s < SEGS; s++)
    psum += totP[base + (size_t)s * D_];
  Vsum[b * D_ + c] = psum;
}

// ---------------- single-pass event scan ------------------------------------
// One ascending pass computes both sides via
//   sum_{e'>q} wd*v = (sufD_seg + totWD_local) - sum_{e'<=q} wd*v
// (queries have skwd=0 -> inclusive==strict at the query). W_OFF p-term is
// the query-independent 0.9*Vsum[b,c]. No second pass, no AVpart round-trip.
__global__ __launch_bounds__(256) void scan_one_k(
    const int* __restrict__ evt_tag, const float* __restrict__ evt_wa,
    const float* __restrict__ evt_wd, const ushort* __restrict__ Vb,
    const float* __restrict__ preA, const float* __restrict__ sufD,
    const float* __restrict__ totWD, const float* __restrict__ Vsum,
    ushort* __restrict__ AVb)
{
  __shared__ ushort Vt[EPB * CW];        // 32 KB: event-major V tile
  __shared__ int sisq[EPB], sidx[EPB], srow[EPB];
  __shared__ float skwa[EPB], skwd[EPB], sqwa[EPB], sqwd[EPB];
  int b = blockIdx.z, seg = blockIdx.y, chunk = blockIdx.x;
  int t = threadIdx.x;
  int e0 = b * 4096 + seg * EPB;
  if (t < EPB) {
    int tg = evt_tag[e0 + t];
    bool isq = (tg & 0x10000) != 0;
    float wa = evt_wa[e0 + t], wd = evt_wd[e0 + t];
    sisq[t] = isq; sidx[t] = isq ? (tg & 0xFFFF) : 0;
    srow[t] = isq ? 0 : (tg & 0xFFFF);
    skwa[t] = isq ? 0.f : wa;  sqwa[t] = wa;
    skwd[t] = isq ? 0.f : wd;  sqwd[t] = wd;
  }
  __syncthreads();
  int c0 = chunk * CW;
  const ushort* vbase = Vb + (size_t)b * N_ * D_ + c0;
#pragma unroll
  for (int r = 0; r < 8; r++) {
    int li = r * 256 + t;
    int e = li >> 5, ch = li & 31;
    gload16(vbase + (size_t)srow[e] * D_ + ch * 8, (char*)Vt + li * 16);
  }
  __syncthreads();

  int cth = c0 + t;
  size_t po = ((size_t)b * SEGS + seg) * D_ + cth;
  float sA   = preA[po];                       // prefix over lower segments
  float sD0  = sufD[po] + totWD[po];           // suffix-higher + local total
  float voff = 0.9f * Vsum[b * D_ + cth];      // W_OFF * sum_all_keys V
  float sDacc = 0.f;
  ushort* AVbrow = AVb + (size_t)b * N_ * D_ + cth;

#pragma unroll 4
  for (int e = 0; e < EPB; e++) {
    float v = bf2f(Vt[e * CW + t]);
    if (sisq[e]) {
      float out = voff + 0.9f * (sqwd[e] * (sD0 - sDacc) - sqwa[e] * sA);
      AVbrow[(size_t)sidx[e] * D_] = f2bf(out);
    }
    sA    += skwa[e] * v;
    sDacc += skwd[e] * v;
  }
}

extern "C" void kernel_launch(void* const* d_in, const int* in_sizes, int n_in,
                              void* d_out, int out_size, void* d_ws, size_t ws_size,
                              hipStream_t stream) {
  (void)in_sizes; (void)n_in; (void)out_size; (void)ws_size;
  const float* x  = (const float*)d_in[0];
  const float* Wq = (const float*)d_in[1];
  const float* gq = (const float*)d_in[2];
  const float* bq = (const float*)d_in[3];
  const float* mq = (const float*)d_in[4];
  const float* vq = (const float*)d_in[5];
  const float* Wk = (const float*)d_in[6];
  const float* gk = (const float*)d_in[7];
  const float* bk = (const float*)d_in[8];
  const float* mk = (const float*)d_in[9];
  const float* vk = (const float*)d_in[10];
  const float* Wv = (const float*)d_in[11];
  const float* gv = (const float*)d_in[12];
  const float* bv = (const float*)d_in[13];
  const float* mv = (const float*)d_in[14];
  const float* vv = (const float*)d_in[15];
  const float* Wo = (const float*)d_in[16];
  const float* bo = (const float*)d_in[17];

  char* p = (char*)d_ws;
  auto alloc = [&](size_t n) { char* r = p; p += n; return r; };
  ushort* x16  = (ushort*)alloc((size_t)M_ * D_ * 2);
  ushort* Vb   = (ushort*)alloc((size_t)M_ * D_ * 2);
  ushort* AVb  = (ushort*)alloc((size_t)M_ * D_ * 2);
  ushort* W3T  = (ushort*)alloc((size_t)3 * D_ * D_ * 2);
  ushort* WoT  = (ushort*)alloc((size_t)D_ * D_ * 2);
  float*  rsQ  = (float*)alloc((size_t)M_ * 4);
  float*  rsK  = (float*)alloc((size_t)M_ * 4);
  int*    evt_tag = (int*)alloc((size_t)B_ * 4096 * 4);
  float*  evt_wa  = (float*)alloc((size_t)B_ * 4096 * 4);
  float*  evt_wd  = (float*)alloc((size_t)B_ * 4096 * 4);
  float*  totWA   = (float*)alloc((size_t)B_ * SEGS * D_ * 4);
  float*  totWD   = (float*)alloc((size_t)B_ * SEGS * D_ * 4);
  float*  totP    = (float*)alloc((size_t)B_ * SEGS * D_ * 4);
  float*  preA    = (float*)alloc((size_t)B_ * SEGS * D_ * 4);
  float*  sufD    = (float*)alloc((size_t)B_ * SEGS * D_ * 4);
  float*  VsumW   = (float*)alloc((size_t)B_ * D_ * 4);

  hipMemsetAsync(rsQ, 0, (size_t)2 * M_ * 4, stream);

  conv_x_k<<<(M_ * D_) / 1024, 256, 0, stream>>>((const float4*)x, (ushort4*)x16);
  dim3 tb(32, 8), tg(32, 32, 4);
  transpose_k<<<tg, tb, 0, stream>>>(Wq, Wk, Wv, Wo, W3T, WoT);

  gemm_qkv_k<<<768, 512, 0, stream>>>(x16, W3T, gq, bq, mq, vq,
                                      gk, bk, mk, vk, gv, bv, mv, vv,
                                      rsQ, rsK, Vb);

  rank_events_k<<<dim3(32, B_), 256, 0, stream>>>(rsQ, rsK, evt_tag, evt_wa, evt_wd);

  seg_tot_k<<<dim3(2, SEGS, B_), 256, 0, stream>>>(evt_tag, evt_wa, evt_wd, Vb,
                                                   totWA, totWD, totP);
  seg_prefix_k<<<dim3(D_ / 256, B_), 256, 0, stream>>>(totWA, totWD, totP,
                                                       preA, sufD, VsumW);
  scan_one_k<<<dim3(D_ / CW, SEGS, B_), 256, 0, stream>>>(
      evt_tag, evt_wa, evt_wd, Vb, preA, sufD, totWD, VsumW, AVb);

  gemm_out_k<<<256, 512, 0, stream>>>(AVb, WoT, (float*)d_out, bo);
}

// Round 7
// 384.777 us; speedup vs baseline: 4.1146x; 4.1146x over previous
//
#include <hip/hip_runtime.h>

#define B_ 8
#define N_ 2048
#define D_ 1024
#define M_ (B_*N_)          // 16384 rows
#define SEGS 64
#define EPB (4096/SEGS)     // 64 events per segment
#define CW 256              // scan chunk width (cols per block)

typedef __attribute__((ext_vector_type(8))) short short8;
typedef __attribute__((ext_vector_type(4))) float floatx4;

__device__ __forceinline__ ushort f2bf(float f) {
  unsigned u = __builtin_bit_cast(unsigned, f);
  return (ushort)((u + 0x7fffu + ((u >> 16) & 1u)) >> 16);
}
__device__ __forceinline__ float bf2f(ushort u) {
  return __builtin_bit_cast(float, ((unsigned)u) << 16);
}
__device__ __forceinline__ void gload16(const void* g, void* l) {
  __builtin_amdgcn_global_load_lds(
      (const __attribute__((address_space(1))) unsigned*)g,
      (__attribute__((address_space(3))) unsigned*)l, 16, 0, 0);
}
__device__ __forceinline__ float sig4(float h) {
  // sigmoid(4*(h-1))
  return 1.0f / (1.0f + __expf(4.0f - 4.0f*h));
}

// ---------------- conversions ----------------
__global__ __launch_bounds__(256) void conv_x_k(const float4* __restrict__ x,
                                                ushort4* __restrict__ o) {
  int i = blockIdx.x * 256 + threadIdx.x;
  float4 f = x[i];
  ushort4 u;
  u.x = f2bf(f.x); u.y = f2bf(f.y); u.z = f2bf(f.z); u.w = f2bf(f.w);
  o[i] = u;
}

// all 4 weight transposes in one launch; z selects the matrix
__global__ __launch_bounds__(256) void transpose_k(
    const float* __restrict__ Wq, const float* __restrict__ Wk,
    const float* __restrict__ Wv, const float* __restrict__ Wo,
    ushort* __restrict__ W3T, ushort* __restrict__ WoT) {
  __shared__ float tile[32][33];
  int z = blockIdx.z;
  const float* W = (z == 0) ? Wq : (z == 1) ? Wk : (z == 2) ? Wv : Wo;
  ushort* WT = (z < 3) ? (W3T + (size_t)z * D_ * D_) : WoT;
  int tx = threadIdx.x, ty = threadIdx.y;
  int x = blockIdx.x * 32 + tx;
  int y = blockIdx.y * 32 + ty;
#pragma unroll
  for (int j = 0; j < 32; j += 8)
    tile[ty + j][tx] = W[(size_t)(y + j) * D_ + x];
  __syncthreads();
  int x2 = blockIdx.y * 32 + tx;
  int y2 = blockIdx.x * 32 + ty;
#pragma unroll
  for (int j = 0; j < 32; j += 8)
    WT[(size_t)(y2 + j) * D_ + x2] = f2bf(tile[tx][ty + j]);
}

// ---------------- 256x256 8-wave GEMM mainloop: BK=64, 2-slot, 1 bar/tile ---
// ROUND-7: round-6's launch_bounds(512,4) capped regs at 128 -> acc spilled
// to scratch (4.6 GB HBM traffic, 3.8% MfmaUtil). 2 blocks/CU is register-
// infeasible for a 256^2 tile (8 waves x ~210 regs > 512/SIMD pool) -- so we
// stay 1 block/CU at launch_bounds(512,2) and attack dead time instead:
// r5 spent ~3400 cy/K-tile vs ~1700 cy of work, concentrated at 3 barrier
// events/tile x 32 tiles. BK=64 halves the tile count (16) and this shape
// has ONE vmcnt(0)+barrier per tile (16 barrier events total, was 96).
//
// Per tile t (NT=16):
//   s_waitcnt vmcnt(0)  (tile t's 8 gloads, issued ~1.5 phases ago - free)
//   s_barrier           -> slot t&1 readable by all waves
//   read half0 frags (12x ds_read_b128)
//   issue 8 gloads(t+1) -> slot (t+1)&1  [readers of that slot were tile
//     t-1; their data fed MFMAs before each wave's barrier arrival -> done]
//   MFMA half0 (32, setprio) ; read half1 frags (12) ; MFMA half1 (32)
//
// LDS per slot: 256 rows x 64 bf16 (128 B = 8 x 16B chunks per row).
// Physical chunk c of row r holds logical chunk (c - r) & 7 (round-0 scheme,
// verified SQ_LDS_BANK_CONFLICT=0): rows 0-7 cover all 8 chunk slots ->
// 2 lanes/16B-slot on a 16-row ds_read_b128 group (2-way aliasing is free).
// global_load_lds writes linearly; inverse swizzle on the global source.
__device__ __forceinline__ void mainloop256(
    const ushort* __restrict__ Ab, const ushort* __restrict__ Bb,
    ushort* __restrict__ As, ushort* __restrict__ Bs, int t,
    floatx4 (&acc)[8][4])
{
  const int lane = t & 63, wid = t >> 6;
  const int quad = lane >> 4, l15 = lane & 15;
  const int wm = wid >> 2, wn = wid & 3;

  // staging: li = r*512+t enumerates 2048 16B chunks of one 32KB slot
  int srcO[4], dsto[4];
#pragma unroll
  for (int r = 0; r < 4; r++) {
    int li = r * 512 + t;
    int row = li >> 3, c = li & 7;
    int soff = ((c - row) & 7) * 8;              // inverse swizzle on source
    srcO[r] = row * D_ + soff;
    dsto[r] = li * 16;
  }

  // fragment read offsets (ushort units): [half][i]
  int offA[2][8], offB[2][4];
#pragma unroll
  for (int h = 0; h < 2; h++) {
#pragma unroll
    for (int i = 0; i < 8; i++) {
      int row = wm * 128 + i * 16 + l15;
      int p = (h * 4 + quad + row) & 7;
      offA[h][i] = row * 64 + p * 8;
    }
#pragma unroll
    for (int i = 0; i < 4; i++) {
      int row = wn * 64 + i * 16 + l15;
      int p = (h * 4 + quad + row) & 7;
      offB[h][i] = row * 64 + p * 8;
    }
  }

  // prologue: stage tile 0 into slot 0 (8 gloads/thread... 4A+4B)
#pragma unroll
  for (int r = 0; r < 4; r++) {
    gload16(Ab + srcO[r], (char*)As + dsto[r]);
    gload16(Bb + srcO[r], (char*)Bs + dsto[r]);
  }

  const int NT = D_ / 64;  // 16 K-tiles
  for (int tt = 0; tt < NT; tt++) {
    asm volatile("s_waitcnt vmcnt(0)" ::: "memory");
    __builtin_amdgcn_s_barrier();
    const ushort* Asl = As + (tt & 1) * 16384;
    const ushort* Bsl = Bs + (tt & 1) * 16384;

    // half 0 fragment reads
    short8 af[4], ag[4], bfr[4];
#pragma unroll
    for (int i = 0; i < 4; i++) af[i] = *(const short8*)(Asl + offA[0][i]);
#pragma unroll
    for (int i = 0; i < 4; i++) ag[i] = *(const short8*)(Asl + offA[0][4 + i]);
#pragma unroll
    for (int i = 0; i < 4; i++) bfr[i] = *(const short8*)(Bsl + offB[0][i]);

    // prefetch tile t+1 into the other slot (overlaps the MFMAs below)
    if (tt + 1 < NT) {
      ushort* dA = As + ((tt + 1) & 1) * 16384;
      ushort* dB = Bs + ((tt + 1) & 1) * 16384;
#pragma unroll
      for (int r = 0; r < 4; r++) {
        gload16(Ab + srcO[r] + (tt + 1) * 64, (char*)dA + dsto[r]);
        gload16(Bb + srcO[r] + (tt + 1) * 64, (char*)dB + dsto[r]);
      }
    }

    __builtin_amdgcn_s_setprio(1);
#pragma unroll
    for (int tm = 0; tm < 4; tm++)
#pragma unroll
      for (int tn = 0; tn < 4; tn++)
        acc[tm][tn] = __builtin_amdgcn_mfma_f32_16x16x32_bf16(
            af[tm], bfr[tn], acc[tm][tn], 0, 0, 0);
#pragma unroll
    for (int tm = 0; tm < 4; tm++)
#pragma unroll
      for (int tn = 0; tn < 4; tn++)
        acc[4 + tm][tn] = __builtin_amdgcn_mfma_f32_16x16x32_bf16(
            ag[tm], bfr[tn], acc[4 + tm][tn], 0, 0, 0);
    __builtin_amdgcn_s_setprio(0);

    // half 1
#pragma unroll
    for (int i = 0; i < 4; i++) af[i] = *(const short8*)(Asl + offA[1][i]);
#pragma unroll
    for (int i = 0; i < 4; i++) ag[i] = *(const short8*)(Asl + offA[1][4 + i]);
#pragma unroll
    for (int i = 0; i < 4; i++) bfr[i] = *(const short8*)(Bsl + offB[1][i]);
    __builtin_amdgcn_s_setprio(1);
#pragma unroll
    for (int tm = 0; tm < 4; tm++)
#pragma unroll
      for (int tn = 0; tn < 4; tn++)
        acc[tm][tn] = __builtin_amdgcn_mfma_f32_16x16x32_bf16(
            af[tm], bfr[tn], acc[tm][tn], 0, 0, 0);
#pragma unroll
    for (int tm = 0; tm < 4; tm++)
#pragma unroll
      for (int tn = 0; tn < 4; tn++)
        acc[4 + tm][tn] = __builtin_amdgcn_mfma_f32_16x16x32_bf16(
            ag[tm], bfr[tn], acc[4 + tm][tn], 0, 0, 0);
    __builtin_amdgcn_s_setprio(0);
  }
}

// ---------------- fused QKV GEMM, 256^2 tile, XCD-aware ----------------
// 768 blocks: xcd = lin&7; 96 slots/XCD = 3 z x 8 m-groups x 4 n-tiles.
__global__ __launch_bounds__(512, 2) void gemm_qkv_k(
    const ushort* __restrict__ A, const ushort* __restrict__ W3T,
    const float* __restrict__ gq, const float* __restrict__ bq,
    const float* __restrict__ mq, const float* __restrict__ vq,
    const float* __restrict__ gk, const float* __restrict__ bk,
    const float* __restrict__ mk, const float* __restrict__ vk,
    const float* __restrict__ gv, const float* __restrict__ bv,
    const float* __restrict__ mv, const float* __restrict__ vv,
    float* __restrict__ rsQ, float* __restrict__ rsK, ushort* __restrict__ Vb)
{
  __shared__ ushort As[2 * 16384];   // 64 KB
  __shared__ ushort Bs[2 * 16384];   // 64 KB
  const int t = threadIdx.x;
  const int lane = t & 63, wid = t >> 6;
  const int quad = lane >> 4, l15 = lane & 15;
  const int wm = wid >> 2, wn = wid & 3;

  const int lin = blockIdx.x;
  const int xcd = lin & 7, s = lin >> 3;   // 96 slots per XCD
  const int z = s >> 5;                    // 0..2
  const int rem = s & 31;
  const int mg = rem >> 2;                 // 0..7
  const int nt = rem & 3;                  // 0..3
  const int tileM = (xcd * 8 + mg) * 256;
  const int tileN = nt * 256;

  floatx4 acc[8][4];
#pragma unroll
  for (int i = 0; i < 8; i++)
#pragma unroll
    for (int j = 0; j < 4; j++) acc[i][j] = (floatx4){0.f, 0.f, 0.f, 0.f};

  mainloop256(A + (size_t)tileM * D_,
              W3T + (size_t)z * D_ * D_ + (size_t)tileN * D_,
              As, Bs, t, acc);

  // BN params in the epilogue (keeps mainloop VGPR pressure minimal)
  const float* gg  = (z == 0) ? gq : (z == 1) ? gk : gv;
  const float* bb  = (z == 0) ? bq : (z == 1) ? bk : bv;
  const float* mmn = (z == 0) ? mq : (z == 1) ? mk : mv;
  const float* vvn = (z == 0) ? vq : (z == 1) ? vk : vv;
  float sc[4], sh[4];
#pragma unroll
  for (int tn = 0; tn < 4; tn++) {
    int col = tileN + wn * 64 + tn * 16 + l15;
    float scv = gg[col] * rsqrtf(vvn[col] + 1e-5f);
    sc[tn] = scv;
    sh[tn] = bb[col] - mmn[col] * scv;
  }

  if (z == 2) {
#pragma unroll
    for (int tm = 0; tm < 8; tm++) {
      int row0 = tileM + wm * 128 + tm * 16 + quad * 4;
#pragma unroll
      for (int tn = 0; tn < 4; tn++) {
        int col = tileN + wn * 64 + tn * 16 + l15;
#pragma unroll
        for (int r = 0; r < 4; r++)
          Vb[(size_t)(row0 + r) * D_ + col] =
              f2bf(sig4(acc[tm][tn][r] * sc[tn] + sh[tn]));
      }
    }
  } else {
    float* rowsum = (z == 0) ? rsQ : rsK;
#pragma unroll
    for (int tm = 0; tm < 8; tm++) {
      float rs[4] = {0.f, 0.f, 0.f, 0.f};
#pragma unroll
      for (int tn = 0; tn < 4; tn++)
#pragma unroll
        for (int r = 0; r < 4; r++)
          rs[r] += sig4(acc[tm][tn][r] * sc[tn] + sh[tn]);
#pragma unroll
      for (int off = 1; off < 16; off <<= 1)
#pragma unroll
        for (int r = 0; r < 4; r++)
          rs[r] += __shfl_xor(rs[r], off, 64);
      if (l15 == 0) {
        int row0 = tileM + wm * 128 + tm * 16 + quad * 4;
#pragma unroll
        for (int r = 0; r < 4; r++)
          atomicAdd(&rowsum[row0 + r], rs[r]);
      }
    }
  }
}

// ---------------- final GEMM: AVb @ WoT^T + bo -> fp32, 256^2 tile ----------
__global__ __launch_bounds__(512, 2) void gemm_out_k(
    const ushort* __restrict__ A, const ushort* __restrict__ Bt,
    float* __restrict__ outF, const float* __restrict__ bo)
{
  __shared__ ushort As[2 * 16384];
  __shared__ ushort Bs[2 * 16384];
  const int t = threadIdx.x;
  const int lane = t & 63, wid = t >> 6;
  const int quad = lane >> 4, l15 = lane & 15;
  const int wm = wid >> 2, wn = wid & 3;

  const int lin = blockIdx.x;
  const int xcd = lin & 7, s = lin >> 3;   // 32 slots per XCD
  const int mg = s >> 2, nt = s & 3;
  const int tileM = (xcd * 8 + mg) * 256;
  const int tileN = nt * 256;

  floatx4 acc[8][4];
#pragma unroll
  for (int i = 0; i < 8; i++)
#pragma unroll
    for (int j = 0; j < 4; j++) acc[i][j] = (floatx4){0.f, 0.f, 0.f, 0.f};

  mainloop256(A + (size_t)tileM * D_, Bt + (size_t)tileN * D_, As, Bs, t, acc);

#pragma unroll
  for (int tn = 0; tn < 4; tn++) {
    int col = tileN + wn * 64 + tn * 16 + l15;
    float bias = bo[col];
#pragma unroll
    for (int tm = 0; tm < 8; tm++) {
      int row0 = tileM + wm * 128 + tm * 16 + quad * 4;
#pragma unroll
      for (int r = 0; r < 4; r++)
        outF[(size_t)(row0 + r) * D_ + col] = acc[tm][tn][r] + bias;
    }
  }
}

// ---------------- rank-by-counting event sort ----------------
__global__ __launch_bounds__(256) void rank_events_k(
    const float* __restrict__ rsQ, const float* __restrict__ rsK,
    int* __restrict__ evt_tag, float* __restrict__ evt_wa, float* __restrict__ evt_wd)
{
  __shared__ unsigned long long keys[4096];  // 32 KB
  __shared__ int part[256];
  int b = blockIdx.y, chunk = blockIdx.x;
  int t = threadIdx.x;
  for (int i = t; i < 4096; i += 256) {
    float v; unsigned tag;
    if (i < 2048) {
      v = 1.0f - rsQ[b * N_ + i] * (1.0f / 1024.0f);
      tag = (unsigned)i | 0x10000u;          // query
    } else {
      int j = i - 2048;
      v = 1.0f - rsK[b * N_ + j] * (1.0f / 1024.0f);
      tag = (unsigned)j;                     // key
    }
    keys[i] = ((unsigned long long)__builtin_bit_cast(unsigned, v) << 32) | tag;
  }
  __syncthreads();
  int e = chunk * 128 + (t & 127);
  int j0 = (t >> 7) * 2048;
  unsigned long long me = keys[e];
  int r = 0;
#pragma unroll 8
  for (int j = 0; j < 2048; j++) r += (keys[j0 + j] < me) ? 1 : 0;
  part[t] = r;
  __syncthreads();
  if (t < 128) {
    int rank = part[t] + part[t + 128];
    unsigned tag = (unsigned)(me & 0x1FFFFu);
    float v = __builtin_bit_cast(float, (unsigned)(me >> 32));
    bool isq = (tag & 0x10000u) != 0;
    int o = b * 4096 + rank;
    evt_tag[o] = (int)tag;
    // keys: wa=e^{2tk}, wd=e^{-2tk};  queries: wa=e^{-2tq}, wd=e^{2tq}
    evt_wa[o] = isq ? expf(-2.0f * v) : expf(2.0f * v);
    evt_wd[o] = isq ? expf(2.0f * v) : expf(-2.0f * v);
  }
}

// ---------------- segment totals (branch-free, pipelined) ----------------
__global__ __launch_bounds__(256) void seg_tot_k(
    const int* __restrict__ evt_tag, const float* __restrict__ evt_wa,
    const float* __restrict__ evt_wd, const ushort* __restrict__ Vb,
    float* __restrict__ totWA, float* __restrict__ totWD, float* __restrict__ totP)
{
  __shared__ int srow[EPB];
  __shared__ float swa[EPB], swd[EPB], spw[EPB];
  int b = blockIdx.z, seg = blockIdx.y, chunk = blockIdx.x;
  int t = threadIdx.x;
  int e0 = b * 4096 + seg * EPB;
  if (t < EPB) {
    int tg = evt_tag[e0 + t];
    bool isk = !(tg & 0x10000);
    srow[t] = isk ? (tg & 0xFFFF) : 0;
    swa[t] = isk ? evt_wa[e0 + t] : 0.f;
    swd[t] = isk ? evt_wd[e0 + t] : 0.f;
    spw[t] = isk ? 1.f : 0.f;
  }
  __syncthreads();
  int c = chunk * 512 + t * 2;
  const ushort* vb = Vb + (size_t)b * N_ * D_ + c;
  float wa0 = 0, wa1 = 0, wd0 = 0, wd1 = 0, p0 = 0, p1 = 0;
#pragma unroll 8
  for (int e = 0; e < EPB; e++) {
    unsigned raw = *(const unsigned*)(vb + (size_t)srow[e] * D_);
    float v0 = bf2f((ushort)(raw & 0xffffu)), v1 = bf2f((ushort)(raw >> 16));
    float wa = swa[e], wd = swd[e], pw = spw[e];
    wa0 += wa * v0; wa1 += wa * v1;
    wd0 += wd * v0; wd1 += wd * v1;
    p0 += pw * v0;  p1 += pw * v1;
  }
  size_t o = ((size_t)b * SEGS + seg) * D_ + c;
  totWA[o] = wa0; totWA[o + 1] = wa1;
  totWD[o] = wd0; totWD[o + 1] = wd1;
  totP[o]  = p0;  totP[o + 1]  = p1;
}

// ---------------- cross-segment prefix/suffix: register-resident scan -------
__global__ __launch_bounds__(256) void seg_prefix_k(
    const float* __restrict__ totWA, const float* __restrict__ totWD,
    const float* __restrict__ totP,
    float* __restrict__ preA, float* __restrict__ sufD,
    float* __restrict__ Vsum)
{
  int b = blockIdx.y;
  int c = blockIdx.x * 256 + threadIdx.x;
  size_t base = (size_t)b * SEGS * D_ + c;

  float va[SEGS];
#pragma unroll
  for (int s = 0; s < SEGS; s++)
    va[s] = totWA[base + (size_t)s * D_];
  float a = 0.f;
#pragma unroll
  for (int s = 0; s < SEGS; s++) {
    preA[base + (size_t)s * D_] = a;
    a += va[s];
  }

#pragma unroll
  for (int s = 0; s < SEGS; s++)
    va[s] = totWD[base + (size_t)s * D_];
  float d = 0.f;
#pragma unroll
  for (int s = SEGS - 1; s >= 0; s--) {
    sufD[base + (size_t)s * D_] = d;
    d += va[s];
  }

  float psum = 0.f;
#pragma unroll
  for (int s = 0; s < SEGS; s++)
    psum += totP[base + (size_t)s * D_];
  Vsum[b * D_ + c] = psum;
}

// ---------------- single-pass event scan ------------------------------------
// One ascending pass computes both sides via
//   sum_{e'>q} wd*v = (sufD_seg + totWD_local) - sum_{e'<=q} wd*v
// (queries have skwd=0 -> inclusive==strict at the query). W_OFF p-term is
// the query-independent 0.9*Vsum[b,c]. No second pass, no AVpart round-trip.
__global__ __launch_bounds__(256) void scan_one_k(
    const int* __restrict__ evt_tag, const float* __restrict__ evt_wa,
    const float* __restrict__ evt_wd, const ushort* __restrict__ Vb,
    const float* __restrict__ preA, const float* __restrict__ sufD,
    const float* __restrict__ totWD, const float* __restrict__ Vsum,
    ushort* __restrict__ AVb)
{
  __shared__ ushort Vt[EPB * CW];        // 32 KB: event-major V tile
  __shared__ int sisq[EPB], sidx[EPB], srow[EPB];
  __shared__ float skwa[EPB], skwd[EPB], sqwa[EPB], sqwd[EPB];
  int b = blockIdx.z, seg = blockIdx.y, chunk = blockIdx.x;
  int t = threadIdx.x;
  int e0 = b * 4096 + seg * EPB;
  if (t < EPB) {
    int tg = evt_tag[e0 + t];
    bool isq = (tg & 0x10000) != 0;
    float wa = evt_wa[e0 + t], wd = evt_wd[e0 + t];
    sisq[t] = isq; sidx[t] = isq ? (tg & 0xFFFF) : 0;
    srow[t] = isq ? 0 : (tg & 0xFFFF);
    skwa[t] = isq ? 0.f : wa;  sqwa[t] = wa;
    skwd[t] = isq ? 0.f : wd;  sqwd[t] = wd;
  }
  __syncthreads();
  int c0 = chunk * CW;
  const ushort* vbase = Vb + (size_t)b * N_ * D_ + c0;
#pragma unroll
  for (int r = 0; r < 8; r++) {
    int li = r * 256 + t;
    int e = li >> 5, ch = li & 31;
    gload16(vbase + (size_t)srow[e] * D_ + ch * 8, (char*)Vt + li * 16);
  }
  __syncthreads();

  int cth = c0 + t;
  size_t po = ((size_t)b * SEGS + seg) * D_ + cth;
  float sA   = preA[po];                       // prefix over lower segments
  float sD0  = sufD[po] + totWD[po];           // suffix-higher + local total
  float voff = 0.9f * Vsum[b * D_ + cth];      // W_OFF * sum_all_keys V
  float sDacc = 0.f;
  ushort* AVbrow = AVb + (size_t)b * N_ * D_ + cth;

#pragma unroll 4
  for (int e = 0; e < EPB; e++) {
    float v = bf2f(Vt[e * CW + t]);
    if (sisq[e]) {
      float out = voff + 0.9f * (sqwd[e] * (sD0 - sDacc) - sqwa[e] * sA);
      AVbrow[(size_t)sidx[e] * D_] = f2bf(out);
    }
    sA    += skwa[e] * v;
    sDacc += skwd[e] * v;
  }
}

extern "C" void kernel_launch(void* const* d_in, const int* in_sizes, int n_in,
                              void* d_out, int out_size, void* d_ws, size_t ws_size,
                              hipStream_t stream) {
  (void)in_sizes; (void)n_in; (void)out_size; (void)ws_size;
  const float* x  = (const float*)d_in[0];
  const float* Wq = (const float*)d_in[1];
  const float* gq = (const float*)d_in[2];
  const float* bq = (const float*)d_in[3];
  const float* mq = (const float*)d_in[4];
  const float* vq = (const float*)d_in[5];
  const float* Wk = (const float*)d_in[6];
  const float* gk = (const float*)d_in[7];
  const float* bk = (const float*)d_in[8];
  const float* mk = (const float*)d_in[9];
  const float* vk = (const float*)d_in[10];
  const float* Wv = (const float*)d_in[11];
  const float* gv = (const float*)d_in[12];
  const float* bv = (const float*)d_in[13];
  const float* mv = (const float*)d_in[14];
  const float* vv = (const float*)d_in[15];
  const float* Wo = (const float*)d_in[16];
  const float* bo = (const float*)d_in[17];

  char* p = (char*)d_ws;
  auto alloc = [&](size_t n) { char* r = p; p += n; return r; };
  ushort* x16  = (ushort*)alloc((size_t)M_ * D_ * 2);
  ushort* Vb   = (ushort*)alloc((size_t)M_ * D_ * 2);
  ushort* AVb  = (ushort*)alloc((size_t)M_ * D_ * 2);
  ushort* W3T  = (ushort*)alloc((size_t)3 * D_ * D_ * 2);
  ushort* WoT  = (ushort*)alloc((size_t)D_ * D_ * 2);
  float*  rsQ  = (float*)alloc((size_t)M_ * 4);
  float*  rsK  = (float*)alloc((size_t)M_ * 4);
  int*    evt_tag = (int*)alloc((size_t)B_ * 4096 * 4);
  float*  evt_wa  = (float*)alloc((size_t)B_ * 4096 * 4);
  float*  evt_wd  = (float*)alloc((size_t)B_ * 4096 * 4);
  float*  totWA   = (float*)alloc((size_t)B_ * SEGS * D_ * 4);
  float*  totWD   = (float*)alloc((size_t)B_ * SEGS * D_ * 4);
  float*  totP    = (float*)alloc((size_t)B_ * SEGS * D_ * 4);
  float*  preA    = (float*)alloc((size_t)B_ * SEGS * D_ * 4);
  float*  sufD    = (float*)alloc((size_t)B_ * SEGS * D_ * 4);
  float*  VsumW   = (float*)alloc((size_t)B_ * D_ * 4);

  hipMemsetAsync(rsQ, 0, (size_t)2 * M_ * 4, stream);

  conv_x_k<<<(M_ * D_) / 1024, 256, 0, stream>>>((const float4*)x, (ushort4*)x16);
  dim3 tb(32, 8), tg(32, 32, 4);
  transpose_k<<<tg, tb, 0, stream>>>(Wq, Wk, Wv, Wo, W3T, WoT);

  gemm_qkv_k<<<768, 512, 0, stream>>>(x16, W3T, gq, bq, mq, vq,
                                      gk, bk, mk, vk, gv, bv, mv, vv,
                                      rsQ, rsK, Vb);

  rank_events_k<<<dim3(32, B_), 256, 0, stream>>>(rsQ, rsK, evt_tag, evt_wa, evt_wd);

  seg_tot_k<<<dim3(2, SEGS, B_), 256, 0, stream>>>(evt_tag, evt_wa, evt_wd, Vb,
                                                   totWA, totWD, totP);
  seg_prefix_k<<<dim3(D_ / 256, B_), 256, 0, stream>>>(totWA, totWD, totP,
                                                       preA, sufD, VsumW);
  scan_one_k<<<dim3(D_ / CW, SEGS, B_), 256, 0, stream>>>(
      evt_tag, evt_wa, evt_wd, Vb, preA, sufD, totWD, VsumW, AVb);

  gemm_out_k<<<256, 512, 0, stream>>>(AVb, WoT, (float*)d_out, bo);
}